// Round 12
// baseline (1032.778 us; speedup 1.0000x reference)
//
#include <hip/hip_runtime.h>
#include <hip/hip_bf16.h>

// DynamicRouterMoE: N=8192 tokens, C=1024, Hdim=4096, E=16, top-2.
// R12 = R11/R8 base with two independent SCHEDULING changes (no inner-loop
//       semantic edits):
//   1. gemm1: BM 256->128 (BN=256) — 2x finer jobs, half the m-tail waste.
//   2. gemm2: KS2 2->4 with the R8 loop order (un-conflated re-test).

typedef __attribute__((ext_vector_type(4))) float f32x4;
typedef __attribute__((ext_vector_type(8))) __bf16 bf16x8;
typedef __attribute__((ext_vector_type(8))) unsigned short u16x8;

#define NEXP 16
#define CAP  2048
#define CDIM 1024
#define HDIM 4096
#define KS2 4            // split-K factor for gemm2
#define BNG 256          // GEMM tile N (both GEMMs)
#define BM1 128          // gemm1 tile M (new)
#define BM2 256          // gemm2 tile M (R8 value)
#define SLOT 8192        // gemm2 LDS slot: 256 rows x 32 k
#define ASLOT1 4096      // gemm1 A slot: 128 rows x 32 k
#define BSLOT1 8192      // gemm1 B slot: 256 rows x 32 k

__device__ __forceinline__ unsigned short f2bf(float f) {
  return __builtin_bit_cast(unsigned short, (__bf16)f);
}

// Bijective XCD swizzle (requires nwg % 8 == 0; true for all GEMM grids).
__device__ __forceinline__ void xcd_remap(int& bx, int& by, int& bz) {
  const int gx = gridDim.x, gy = gridDim.y;
  const int nwg = gx * gy * gridDim.z;
  int flat = blockIdx.x + gx * (blockIdx.y + gy * blockIdx.z);
  flat = (flat & 7) * (nwg >> 3) + (flat >> 3);
  bx = flat % gx;
  const int t = flat / gx;
  by = t % gy;
  bz = t / gy;
}

// ------- router: 4 tokens/block (wave per token), fused x->bf16 -------------
__global__ __launch_bounds__(256) void router_kernel(
    const float* __restrict__ x, const float* __restrict__ wr,
    float* __restrict__ pair_w, int* __restrict__ counts,
    int* __restrict__ lists, unsigned short* __restrict__ xb)
{
  const int n = blockIdx.x * 4 + (threadIdx.x >> 6);
  const int l = threadIdx.x & 63;
  const float* xrow = x + (size_t)n * CDIM;
  unsigned short* xbrow = xb + (size_t)n * CDIM;
  double acc[NEXP];
#pragma unroll
  for (int e = 0; e < NEXP; e++) acc[e] = 0.0;
  for (int it = 0; it < CDIM / 64; it++) {
    const int c = l + it * 64;
    const float xf = xrow[c];
    xbrow[c] = f2bf(xf);
    const double xv = (double)xf;
    const float* w = wr + c * NEXP;
#pragma unroll
    for (int e = 0; e < NEXP; e++) acc[e] += xv * (double)w[e];
  }
#pragma unroll
  for (int e = 0; e < NEXP; e++) {
    double v = acc[e];
    for (int off = 32; off > 0; off >>= 1) v += __shfl_xor(v, off, 64);
    acc[e] = v;
  }
  if (l == 0) {
    int e0 = 0; double b0 = acc[0];
    for (int e = 1; e < NEXP; e++) if (acc[e] > b0) { b0 = acc[e]; e0 = e; }
    int e1 = -1; double b1v = -1e300;
    for (int e = 0; e < NEXP; e++) {
      if (e == e0) continue;
      if (acc[e] > b1v) { b1v = acc[e]; e1 = e; }
    }
    const double d = exp(b1v - b0);
    pair_w[2 * n]     = (float)(1.0 / (1.0 + d));
    pair_w[2 * n + 1] = (float)(d / (1.0 + d));
    int p0 = atomicAdd(&counts[e0], 1);
    if (p0 < CAP) lists[e0 * CAP + p0] = 2 * n;
    int p1 = atomicAdd(&counts[e1], 1);
    if (p1 < CAP) lists[e1 * CAP + p1] = 2 * n + 1;
  }
}

#define SBAR asm volatile("s_barrier" ::: "memory")

// =================== GEMM1: BM=128, BN=256, 8 waves (64x64 each) ===========
// LDS: A slots [par][h][128][32] (4 x 8KB/2) then B slots [par][h][256][32]
// (4 x 16KB) = 96 KB. Quad-XOR involution q' = q ^ ((row>>1)&3) both sides.
// A staging: thread -> row ar=t>>2, octet aq=t&3; 2 x 16B loads (h0,h1),
//            2 swizzled ds_write_b128. B staging: exact R8 pattern.
// Loop: R8 order — 1 barrier/tile, regs lead by 1 tile, loads lead by 2.

#define LOADA1(kbyte)                                                          \
  do {                                                                         \
    rA0 = *(const u16x8*)(agA + (kbyte));                                      \
    rA1 = *(const u16x8*)(agA + (kbyte) + 64);                                 \
  } while (0)

#define DSWA1(parx)                                                            \
  do {                                                                         \
    *(u16x8*)(&lds[((parx) * 2 + 0) * ASLOT1] + swA) = rA0;                    \
    *(u16x8*)(&lds[((parx) * 2 + 1) * ASLOT1] + swA) = rA1;                    \
  } while (0)

#define LOADB1(ktv)                                                            \
  do {                                                                         \
    _Pragma("unroll")                                                          \
    for (int u = 0; u < 4; u++)                                                \
      _Pragma("unroll")                                                        \
      for (int j = 0; j < 8; j++)                                              \
        rB[u][j] = bgu[u][(size_t)((ktv) + j) * HDIM];                         \
  } while (0)

#define DSWB1(parx)                                                            \
  do {                                                                         \
    unsigned short* SB_ = &lds[4 * ASLOT1 + ((parx) * 2 + bh) * BSLOT1];       \
    _Pragma("unroll")                                                          \
    for (int u = 0; u < 4; u++) {                                              \
      u16x8 v_;                                                                \
      _Pragma("unroll")                                                        \
      for (int j = 0; j < 8; j++) v_[j] = f2bf(rB[u][j]);                      \
      *(u16x8*)(SB_ + brow * 32 + (u ^ bqx) * 8) = v_;                         \
    }                                                                          \
  } while (0)

#define COMPUTE1(parx, hx)                                                     \
  do {                                                                         \
    const unsigned short* As_ = &lds[((parx) * 2 + (hx)) * ASLOT1];            \
    const unsigned short* Bs_ = &lds[4 * ASLOT1 + ((parx) * 2 + (hx)) * BSLOT1]; \
    bf16x8 af[4], bfv[4];                                                      \
    _Pragma("unroll")                                                          \
    for (int mf = 0; mf < 4; mf++)                                             \
      af[mf] = *(const bf16x8*)(As_ + (wrr * 64 + mf * 16 + lrow) * 32 + qsw); \
    _Pragma("unroll")                                                          \
    for (int nf = 0; nf < 4; nf++)                                             \
      bfv[nf] = *(const bf16x8*)(Bs_ + (wc * 64 + nf * 16 + lrow) * 32 + qsw); \
    __builtin_amdgcn_s_setprio(1);                                             \
    _Pragma("unroll")                                                          \
    for (int mf = 0; mf < 4; mf++)                                             \
      _Pragma("unroll")                                                        \
      for (int nf = 0; nf < 4; nf++)                                           \
        acc[mf][nf] = __builtin_amdgcn_mfma_f32_16x16x32_bf16(                 \
            af[mf], bfv[nf], acc[mf][nf], 0, 0, 0);                            \
    __builtin_amdgcn_s_setprio(0);                                             \
  } while (0)

__global__ __launch_bounds__(512, 2) void gemm1_bm_kernel(
    const unsigned short* __restrict__ xb, const float* __restrict__ w1f,
    const float* __restrict__ b1, const int* __restrict__ counts,
    const int* __restrict__ lists, unsigned short* __restrict__ Hb)
{
  int bx, by, bz;
  xcd_remap(bx, by, bz);
  const int e = bz;
  int cnt = counts[e]; if (cnt > CAP) cnt = CAP;
  const int m0 = by * BM1;
  if (m0 >= cnt) return;
  const int n0 = bx * BNG;
  const int* list = lists + e * CAP;
  const float* Wf = w1f + (size_t)e * CDIM * HDIM;

  __shared__ __align__(16) unsigned short lds[4 * ASLOT1 + 4 * BSLOT1]; // 96 KB

  const int t = threadIdx.x, w = t >> 6, lane = t & 63;
  const int wrr = w >> 2, wc = w & 3;         // 2M x 4N waves, each 64x64
  const int lrow = lane & 15, lgrp = lane >> 4;
  const int qsw = (lgrp ^ ((lrow >> 1) & 3)) * 8;

  // A staging: row ar = t>>2 (0..127), octet aq = t&3 in each 32k half
  const int ar = t >> 2, aq = t & 3, aqx = (t >> 3) & 3;   // aqx = (ar>>1)&3
  const int swA = ar * 32 + (aq ^ aqx) * 8;
  int ai = m0 + ar; if (ai > cnt - 1) ai = cnt - 1;
  const char* agA = (const char*)(xb + (size_t)(list[ai] >> 1) * CDIM) + aq * 16;

  // B staging (fp32 [k][n] -> bf16 [n][k]) — exact R8 geometry
  const int brow = t & 255, bh = t >> 8, bqx = (brow >> 1) & 3;
  const float* bgu[4];
#pragma unroll
  for (int u = 0; u < 4; u++)
    bgu[u] = Wf + (size_t)(bh * 32 + u * 8) * HDIM + n0 + brow;

  f32x4 acc[4][4] = {};

  {
    const int NT = CDIM / 64;
    u16x8 rA0, rA1; float rB[4][8];
    LOADA1(0); LOADB1(0);
    DSWA1(0); DSWB1(0);
    LOADA1(128); LOADB1(64);
    asm volatile("s_waitcnt lgkmcnt(0)" ::: "memory");
    for (int tt = 0; tt < NT; ++tt) {
      const int par = tt & 1;
      SBAR;
      if (tt + 1 < NT) { DSWA1(par ^ 1); DSWB1(par ^ 1); }
      if (tt + 2 < NT) { LOADA1((tt + 2) * 128); LOADB1((tt + 2) * 64); }
      COMPUTE1(par, 0);
      COMPUTE1(par, 1);
    }
  }

  // epilogue: +b1, relu, bf16 scatter to Hb rows = pair ids
  int hrow[4][4]; bool valid[4][4];
#pragma unroll
  for (int mf = 0; mf < 4; mf++)
#pragma unroll
    for (int rr = 0; rr < 4; rr++) {
      const int mi = m0 + wrr * 64 + mf * 16 + lgrp * 4 + rr;
      valid[mf][rr] = (mi < cnt);
      hrow[mf][rr] = list[valid[mf][rr] ? mi : (cnt - 1)];
    }
#pragma unroll
  for (int nf = 0; nf < 4; nf++) {
    const int col = n0 + wc * 64 + nf * 16 + lrow;
    const float bias = b1[e * HDIM + col];
#pragma unroll
    for (int mf = 0; mf < 4; mf++)
#pragma unroll
      for (int rr = 0; rr < 4; rr++)
        if (valid[mf][rr]) {
          float h = acc[mf][nf][rr] + bias;
          h = h > 0.f ? h : 0.f;
          Hb[(size_t)hrow[mf][rr] * HDIM + col] = f2bf(h);
        }
  }
}

// =================== GEMM2: exact R8 body, KS2=4 ===========================
#define LOADA(kbyte)                                                           \
  do {                                                                         \
    rA0 = *(const u16x8*)(ag0 + (kbyte));                                      \
    rA1 = *(const u16x8*)(ag1 + (kbyte));                                      \
    rA2 = *(const u16x8*)(ag0 + (kbyte) + 64);                                 \
    rA3 = *(const u16x8*)(ag1 + (kbyte) + 64);                                 \
  } while (0)

#define DSWA(parx)                                                             \
  do {                                                                         \
    unsigned short* S0_ = &lds[((parx) * 2 + 0) * SLOT];                       \
    unsigned short* S1_ = &lds[((parx) * 2 + 1) * SLOT];                       \
    *(u16x8*)(S0_ + sw0) = rA0;                                                \
    *(u16x8*)(S0_ + sw1) = rA1;                                                \
    *(u16x8*)(S1_ + sw0) = rA2;                                                \
    *(u16x8*)(S1_ + sw1) = rA3;                                                \
  } while (0)

#define LOADB(ktv)                                                             \
  do {                                                                         \
    _Pragma("unroll")                                                          \
    for (int u = 0; u < 4; u++)                                                \
      _Pragma("unroll")                                                        \
      for (int j = 0; j < 8; j++)                                              \
        rB[u][j] = bgu[u][(size_t)((ktv) + j) * CDIM];                         \
  } while (0)

#define DSWB(parx)                                                             \
  do {                                                                         \
    unsigned short* SB_ = &lds[4 * SLOT + ((parx) * 2 + bh) * SLOT];           \
    _Pragma("unroll")                                                          \
    for (int u = 0; u < 4; u++) {                                              \
      u16x8 v_;                                                                \
      _Pragma("unroll")                                                        \
      for (int j = 0; j < 8; j++) v_[j] = f2bf(rB[u][j]);                      \
      *(u16x8*)(SB_ + brow * 32 + (u ^ bqx) * 8) = v_;                         \
    }                                                                          \
  } while (0)

#define COMPUTE2(parx, hx)                                                     \
  do {                                                                         \
    const unsigned short* As_ = &lds[((parx) * 2 + (hx)) * SLOT];              \
    const unsigned short* Bs_ = &lds[4 * SLOT + ((parx) * 2 + (hx)) * SLOT];   \
    bf16x8 af[8], bfv[4];                                                      \
    _Pragma("unroll")                                                          \
    for (int mf = 0; mf < 8; mf++)                                             \
      af[mf] = *(const bf16x8*)(As_ + (wr * 128 + mf * 16 + lrow) * 32 + qsw); \
    _Pragma("unroll")                                                          \
    for (int nf = 0; nf < 4; nf++)                                             \
      bfv[nf] = *(const bf16x8*)(Bs_ + (wc * 64 + nf * 16 + lrow) * 32 + qsw); \
    __builtin_amdgcn_s_setprio(1);                                             \
    _Pragma("unroll")                                                          \
    for (int mf = 0; mf < 8; mf++)                                             \
      _Pragma("unroll")                                                        \
      for (int nf = 0; nf < 4; nf++)                                           \
        acc[mf][nf] = __builtin_amdgcn_mfma_f32_16x16x32_bf16(                 \
            af[mf], bfv[nf], acc[mf][nf], 0, 0, 0);                            \
    __builtin_amdgcn_s_setprio(0);                                             \
  } while (0)

__global__ __launch_bounds__(512, 2) void gemm2_8p_kernel(
    const unsigned short* __restrict__ Hb, const float* __restrict__ w2f,
    const float* __restrict__ b2, const float* __restrict__ pair_w,
    const int* __restrict__ counts, const int* __restrict__ lists,
    float* __restrict__ out)
{
  int bx, by, bz;
  xcd_remap(bx, by, bz);
  const int e = bz / KS2, ks = bz % KS2;
  int cnt = counts[e]; if (cnt > CAP) cnt = CAP;
  const int m0 = by * BM2;
  if (m0 >= cnt) return;
  const int n0 = bx * BNG;
  const int* list = lists + e * CAP;
  const float* Wf = w2f + (size_t)e * HDIM * CDIM;
  const int kbeg = ks * (HDIM / KS2);

  __shared__ __align__(16) unsigned short lds[8 * SLOT];  // 128 KB

  const int t = threadIdx.x, w = t >> 6, lane = t & 63;
  const int wr = w >> 2, wc = w & 3;
  const int lrow = lane & 15, lgrp = lane >> 4;
  const int qsw = (lgrp ^ ((lrow >> 1) & 3)) * 8;

  const int sr0 = w * 16 + (lane >> 2), sr1 = 128 + sr0;
  const int wq = ((lane & 3) ^ ((lane >> 3) & 3)) * 8;
  const int sw0 = sr0 * 32 + wq, sw1 = sr1 * 32 + wq;
  int ai0 = m0 + sr0; if (ai0 > cnt - 1) ai0 = cnt - 1;
  int ai1 = m0 + sr1; if (ai1 > cnt - 1) ai1 = cnt - 1;
  const char* ag0 = (const char*)(Hb + (size_t)list[ai0] * HDIM + kbeg) + (lane & 3) * 16;
  const char* ag1 = (const char*)(Hb + (size_t)list[ai1] * HDIM + kbeg) + (lane & 3) * 16;

  const int brow = t & 255, bh = t >> 8, bqx = (brow >> 1) & 3;
  const float* bgu[4];
#pragma unroll
  for (int u = 0; u < 4; u++)
    bgu[u] = Wf + (size_t)(kbeg + bh * 32 + u * 8) * CDIM + n0 + brow;

  f32x4 acc[8][4] = {};

  {
    const int NT = (HDIM / KS2) / 64;   // 16
    u16x8 rA0, rA1, rA2, rA3; float rB[4][8];
    LOADA(0); LOADB(0);
    DSWA(0); DSWB(0);
    LOADA(128); LOADB(64);
    asm volatile("s_waitcnt lgkmcnt(0)" ::: "memory");
    for (int tt = 0; tt < NT; ++tt) {
      const int par = tt & 1;
      SBAR;
      if (tt + 1 < NT) { DSWA(par ^ 1); DSWB(par ^ 1); }
      if (tt + 2 < NT) { LOADA((tt + 2) * 128); LOADB((tt + 2) * 64); }
      COMPUTE2(par, 0);
      COMPUTE2(par, 1);
    }
  }

  // epilogue: +b2 (ks==0 only), scale by routing weight, atomic accumulate.
  float wgt[8][4]; int tok[8][4]; bool valid[8][4];
#pragma unroll
  for (int mf = 0; mf < 8; mf++)
#pragma unroll
    for (int rr = 0; rr < 4; rr++) {
      const int mi = m0 + wr * 128 + mf * 16 + lgrp * 4 + rr;
      valid[mf][rr] = (mi < cnt);
      const int p = list[valid[mf][rr] ? mi : (cnt - 1)];
      wgt[mf][rr] = pair_w[p];
      tok[mf][rr] = p >> 1;
    }
#pragma unroll
  for (int nf = 0; nf < 4; nf++) {
    const int col = n0 + wc * 64 + nf * 16 + lrow;
    const float bias = (ks == 0) ? b2[e * CDIM + col] : 0.f;
#pragma unroll
    for (int mf = 0; mf < 8; mf++)
#pragma unroll
      for (int rr = 0; rr < 4; rr++)
        if (valid[mf][rr])
          atomicAdd(out + (size_t)tok[mf][rr] * CDIM + col,
                    wgt[mf][rr] * (acc[mf][nf][rr] + bias));
  }
}

// ================= fallback kernels (fp32 inputs, reg-staged, 128²) =========
__device__ __forceinline__ int swz(int row, int b) {
  return row * 128 + (b ^ (((row >> 1) & 7) << 4));
}

#define MFMA_COMPUTE_F(Abase, Bbase)                                           \
  _Pragma("unroll")                                                            \
  for (int kk = 0; kk < 2; kk++) {                                             \
    bf16x8 af[4], bfr[4];                                                      \
    const int kb = (kk * 32 + lgrp * 8) * 2;                                   \
    _Pragma("unroll")                                                          \
    for (int i = 0; i < 4; i++)                                                \
      af[i] = *(const bf16x8*)((Abase) + swz(wm + i * 16 + lrow, kb));         \
    _Pragma("unroll")                                                          \
    for (int j = 0; j < 4; j++)                                                \
      bfr[j] = *(const bf16x8*)((Bbase) + swz(wn + j * 16 + lrow, kb));        \
    _Pragma("unroll")                                                          \
    for (int i = 0; i < 4; i++)                                                \
      _Pragma("unroll")                                                        \
      for (int j = 0; j < 4; j++)                                              \
        acc[i][j] = __builtin_amdgcn_mfma_f32_16x16x32_bf16(                   \
            af[i], bfr[j], acc[i][j], 0, 0, 0);                                \
  }

__global__ __launch_bounds__(256) void gemm1_f32_kernel(
    const float* __restrict__ x, const float* __restrict__ w1,
    const float* __restrict__ b1, const int* __restrict__ counts,
    const int* __restrict__ lists, unsigned short* __restrict__ Hb,
    int e_base, int h_by_pair)
{
  const int e = e_base + blockIdx.z;
  int cnt = counts[e]; if (cnt > CAP) cnt = CAP;
  const int m0 = blockIdx.y * 128;
  if (m0 >= cnt) return;
  const int n0 = blockIdx.x * 128;
  const int* list = lists + e * CAP;
  const float* W = w1 + (size_t)e * CDIM * HDIM;
  __shared__ __align__(16) unsigned short As[128 * 64];
  __shared__ __align__(16) unsigned short Bs[128 * 64];
  const int t = threadIdx.x;
  const int a_row = t >> 1, a_half = t & 1;
  int a_idx = m0 + a_row; if (a_idx > cnt - 1) a_idx = cnt - 1;
  const float* a_src = x + (size_t)(list[a_idx] >> 1) * CDIM + a_half * 32;
  const int b_np = t & 63, b_kg = t >> 6;
  const int wid = t >> 6, lane = t & 63;
  const int wm = (wid >> 1) * 64, wn = (wid & 1) * 64;
  const int lrow = lane & 15, lgrp = lane >> 4;
  f32x4 acc[4][4] = {};
  for (int kt = 0; kt < CDIM; kt += 64) {
    {
      const float* s = a_src + kt;
      u16x8 cv[4];
#pragma unroll
      for (int q = 0; q < 4; q++) {
        float4 v0 = *(const float4*)(s + q * 8);
        float4 v1 = *(const float4*)(s + q * 8 + 4);
        cv[q][0] = f2bf(v0.x); cv[q][1] = f2bf(v0.y);
        cv[q][2] = f2bf(v0.z); cv[q][3] = f2bf(v0.w);
        cv[q][4] = f2bf(v1.x); cv[q][5] = f2bf(v1.y);
        cv[q][6] = f2bf(v1.z); cv[q][7] = f2bf(v1.w);
      }
#pragma unroll
      for (int q = 0; q < 4; q++)
        *(u16x8*)((char*)As + swz(a_row, (a_half * 32 + q * 8) * 2)) = cv[q];
    }
    {
#pragma unroll
      for (int it = 0; it < 2; it++) {
        const int k0 = (b_kg + 4 * it) * 8;
        u16x8 c0, c1;
#pragma unroll
        for (int j = 0; j < 8; j++) {
          float2 v = *(const float2*)(W + (size_t)(kt + k0 + j) * HDIM + n0 + 2 * b_np);
          c0[j] = f2bf(v.x); c1[j] = f2bf(v.y);
        }
        *(u16x8*)((char*)Bs + swz(2 * b_np,     k0 * 2)) = c0;
        *(u16x8*)((char*)Bs + swz(2 * b_np + 1, k0 * 2)) = c1;
      }
    }
    __syncthreads();
    MFMA_COMPUTE_F((const char*)As, (const char*)Bs)
    __syncthreads();
  }
  int hrow[4][4]; bool valid[4][4];
#pragma unroll
  for (int i = 0; i < 4; i++)
#pragma unroll
    for (int r = 0; r < 4; r++) {
      const int mi = m0 + wm + i * 16 + lgrp * 4 + r;
      valid[i][r] = (mi < cnt);
      const int idx = valid[i][r] ? mi : (cnt - 1);
      hrow[i][r] = h_by_pair ? list[idx] : idx;
    }
#pragma unroll
  for (int j = 0; j < 4; j++) {
    const int col = n0 + wn + j * 16 + lrow;
    const float bias = b1[e * HDIM + col];
#pragma unroll
    for (int i = 0; i < 4; i++)
#pragma unroll
      for (int r = 0; r < 4; r++)
        if (valid[i][r]) {
          float h = acc[i][j][r] + bias;
          h = h > 0.f ? h : 0.f;
          Hb[(size_t)hrow[i][r] * HDIM + col] = f2bf(h);
        }
  }
}

__global__ __launch_bounds__(256) void gemm2_f32_kernel(
    const unsigned short* __restrict__ Hb, const float* __restrict__ w2,
    const float* __restrict__ b2, const float* __restrict__ pair_w,
    const int* __restrict__ counts, const int* __restrict__ lists,
    float* __restrict__ out, int e_base, int h_by_pair)
{
  const int e = e_base + blockIdx.z;
  int cnt = counts[e]; if (cnt > CAP) cnt = CAP;
  const int m0 = blockIdx.y * 128;
  if (m0 >= cnt) return;
  const int n0 = blockIdx.x * 128;
  const int* list = lists + e * CAP;
  const float* W = w2 + (size_t)e * HDIM * CDIM;
  __shared__ __align__(16) unsigned short As[128 * 64];
  __shared__ __align__(16) unsigned short Bs[128 * 64];
  const int t = threadIdx.x;
  const int a_row = t >> 1, a_half = t & 1;
  int a_idx = m0 + a_row; if (a_idx > cnt - 1) a_idx = cnt - 1;
  const unsigned short* a_src =
      Hb + (size_t)(h_by_pair ? list[a_idx] : a_idx) * HDIM + a_half * 32;
  const int b_np = t & 63, b_kg = t >> 6;
  const int wid = t >> 6, lane = t & 63;
  const int wm = (wid >> 1) * 64, wn = (wid & 1) * 64;
  const int lrow = lane & 15, lgrp = lane >> 4;
  f32x4 acc[4][4] = {};
  for (int kt = 0; kt < HDIM; kt += 64) {
    {
      const unsigned short* s = a_src + kt;
#pragma unroll
      for (int q = 0; q < 4; q++) {
        u16x8 v = *(const u16x8*)(s + q * 8);
        *(u16x8*)((char*)As + swz(a_row, (a_half * 32 + q * 8) * 2)) = v;
      }
    }
    {
#pragma unroll
      for (int it = 0; it < 2; it++) {
        const int k0 = (b_kg + 4 * it) * 8;
        u16x8 c0, c1;
#pragma unroll
        for (int j = 0; j < 8; j++) {
          float2 v = *(const float2*)(W + (size_t)(kt + k0 + j) * CDIM + n0 + 2 * b_np);
          c0[j] = f2bf(v.x); c1[j] = f2bf(v.y);
        }
        *(u16x8*)((char*)Bs + swz(2 * b_np,     k0 * 2)) = c0;
        *(u16x8*)((char*)Bs + swz(2 * b_np + 1, k0 * 2)) = c1;
      }
    }
    __syncthreads();
    MFMA_COMPUTE_F((const char*)As, (const char*)Bs)
    __syncthreads();
  }
  float wgt[4][4]; int tok[4][4]; bool valid[4][4];
#pragma unroll
  for (int i = 0; i < 4; i++)
#pragma unroll
    for (int r = 0; r < 4; r++) {
      const int mi = m0 + wm + i * 16 + lgrp * 4 + r;
      valid[i][r] = (mi < cnt);
      const int idx = valid[i][r] ? mi : (cnt - 1);
      const int p = list[idx];
      wgt[i][r] = pair_w[p];
      tok[i][r] = p >> 1;
    }
#pragma unroll
  for (int j = 0; j < 4; j++) {
    const int col = n0 + wn + j * 16 + lrow;
    const float bias = b2[e * CDIM + col];
#pragma unroll
    for (int i = 0; i < 4; i++)
#pragma unroll
      for (int r = 0; r < 4; r++)
        if (valid[i][r])
          atomicAdd(out + (size_t)tok[i][r] * CDIM + col,
                    wgt[i][r] * (acc[i][j][r] + bias));
  }
}

extern "C" void kernel_launch(void* const* d_in, const int* in_sizes, int n_in,
                              void* d_out, int out_size, void* d_ws, size_t ws_size,
                              hipStream_t stream)
{
  const float* x  = (const float*)d_in[0];
  const float* wr = (const float*)d_in[1];
  const float* w1 = (const float*)d_in[2];
  const float* b1 = (const float*)d_in[3];
  const float* w2 = (const float*)d_in[4];
  const float* b2 = (const float*)d_in[5];
  float* out = (float*)d_out;

  const int N = in_sizes[0] / CDIM;  // 8192 tokens

  char* ws = (char*)d_ws;
  int* counts = (int*)ws;
  int* lists  = (int*)(ws + 256);
  float* pw   = (float*)(ws + 256 + NEXP * CAP * 4);
  size_t off = 256 + (size_t)NEXP * CAP * 4 + (size_t)2 * N * 4;
  off = (off + 255) & ~(size_t)255;
  unsigned short* xb = (unsigned short*)(ws + off);
  const size_t xb_sz = (size_t)N * CDIM * 2;
  unsigned short* Hb = (unsigned short*)(ws + off + xb_sz);
  const size_t Hb_sz = (size_t)2 * N * HDIM * 2;

  const size_t need_new = off + xb_sz + Hb_sz;             // ~151 MB
  const size_t need_old = off + Hb_sz;                     // ~134.5 MB

  hipMemsetAsync(d_ws, 0, 64, stream);
  hipMemsetAsync(d_out, 0, (size_t)out_size * 4, stream);

  if (ws_size >= need_new) {
    router_kernel<<<N / 4, 256, 0, stream>>>(x, wr, pw, counts, lists, xb);
    gemm1_bm_kernel<<<dim3(HDIM / BNG, CAP / BM1, NEXP), 512, 0, stream>>>(
        xb, w1, b1, counts, lists, Hb);
    gemm2_8p_kernel<<<dim3(CDIM / BNG, CAP / BM2, NEXP * KS2), 512, 0, stream>>>(
        Hb, w2, b2, pw, counts, lists, out);
  } else if (ws_size >= need_old) {
    unsigned short* Hb0 = (unsigned short*)(ws + off);
    router_kernel<<<N / 4, 256, 0, stream>>>(x, wr, pw, counts, lists, Hb0);
    gemm1_f32_kernel<<<dim3(HDIM / 128, CAP / 128, NEXP), 256, 0, stream>>>(
        x, w1, b1, counts, lists, Hb0, 0, 1);
    gemm2_f32_kernel<<<dim3(CDIM / 128, CAP / 128, NEXP), 256, 0, stream>>>(
        Hb0, w2, b2, pw, counts, lists, out, 0, 1);
  }
}

// Round 13
// 879.072 us; speedup vs baseline: 1.1749x; 1.1749x over previous
//
#include <hip/hip_runtime.h>
#include <hip/hip_bf16.h>

// DynamicRouterMoE: N=8192 tokens, C=1024, Hdim=4096, E=16, top-2.
// R13 = exact R11 (best verified: 880 µs). R12's two scheduling experiments
//       (gemm1 BM=128, gemm2 KS2=4) both regressed and are reverted.
//       Config: 256x256 8-wave reg-staged GEMMs (A bf16, B fp32->bf16
//       in-kernel transpose), quad-XOR LDS swizzle (0 bank conflicts),
//       bijective XCD remap, KS2=2, R8 loop order, 4-token router.

typedef __attribute__((ext_vector_type(4))) float f32x4;
typedef __attribute__((ext_vector_type(8))) __bf16 bf16x8;
typedef __attribute__((ext_vector_type(8))) unsigned short u16x8;

#define NEXP 16
#define CAP  2048
#define CDIM 1024
#define HDIM 4096
#define KS2 2            // split-K factor for gemm2 (verified best)
#define BMG 256          // GEMM tile M
#define BNG 256          // GEMM tile N
#define SLOT 8192        // elems per LDS slot: 256 rows x 32 k

__device__ __forceinline__ unsigned short f2bf(float f) {
  return __builtin_bit_cast(unsigned short, (__bf16)f);
}

// Bijective XCD swizzle (requires nwg % 8 == 0; true for all GEMM grids).
__device__ __forceinline__ void xcd_remap(int& bx, int& by, int& bz) {
  const int gx = gridDim.x, gy = gridDim.y;
  const int nwg = gx * gy * gridDim.z;
  int flat = blockIdx.x + gx * (blockIdx.y + gy * blockIdx.z);
  flat = (flat & 7) * (nwg >> 3) + (flat >> 3);
  bx = flat % gx;
  const int t = flat / gx;
  by = t % gy;
  bz = t / gy;
}

// ------- router: 4 tokens/block (wave per token), fused x->bf16 -------------
__global__ __launch_bounds__(256) void router_kernel(
    const float* __restrict__ x, const float* __restrict__ wr,
    float* __restrict__ pair_w, int* __restrict__ counts,
    int* __restrict__ lists, unsigned short* __restrict__ xb)
{
  const int n = blockIdx.x * 4 + (threadIdx.x >> 6);
  const int l = threadIdx.x & 63;
  const float* xrow = x + (size_t)n * CDIM;
  unsigned short* xbrow = xb + (size_t)n * CDIM;
  double acc[NEXP];
#pragma unroll
  for (int e = 0; e < NEXP; e++) acc[e] = 0.0;
  for (int it = 0; it < CDIM / 64; it++) {
    const int c = l + it * 64;
    const float xf = xrow[c];
    xbrow[c] = f2bf(xf);
    const double xv = (double)xf;
    const float* w = wr + c * NEXP;
#pragma unroll
    for (int e = 0; e < NEXP; e++) acc[e] += xv * (double)w[e];
  }
#pragma unroll
  for (int e = 0; e < NEXP; e++) {
    double v = acc[e];
    for (int off = 32; off > 0; off >>= 1) v += __shfl_xor(v, off, 64);
    acc[e] = v;
  }
  if (l == 0) {
    int e0 = 0; double b0 = acc[0];
    for (int e = 1; e < NEXP; e++) if (acc[e] > b0) { b0 = acc[e]; e0 = e; }
    int e1 = -1; double b1v = -1e300;
    for (int e = 0; e < NEXP; e++) {
      if (e == e0) continue;
      if (acc[e] > b1v) { b1v = acc[e]; e1 = e; }
    }
    const double d = exp(b1v - b0);
    pair_w[2 * n]     = (float)(1.0 / (1.0 + d));
    pair_w[2 * n + 1] = (float)(d / (1.0 + d));
    int p0 = atomicAdd(&counts[e0], 1);
    if (p0 < CAP) lists[e0 * CAP + p0] = 2 * n;
    int p1 = atomicAdd(&counts[e1], 1);
    if (p1 < CAP) lists[e1 * CAP + p1] = 2 * n + 1;
  }
}

// ========= 8-wave 256x256 reg-staged GEMM bodies (exact R8) =================
// LDS: A slots [par][h][256 rows][32 k] then B slots (8 x 16KB = 128KB).
// Stored quad q' holds global quad g = q' ^ ((row>>1)&3)  (R6-verified).
// A: bf16 source, 4 x 16B loads + 4 swizzled ds_write_b128 per tile.
// B: native fp32 [k][n]. Per thread: n-col brow=t&255, k-half bh=t>>8,
//    4 octet-units x 8 k-strided dword loads (wave-coalesced over n),
//    cvt to bf16 in reg, 4 swizzled ds_write_b128 in [n][k] order.
// Loop: 1 barrier/tile; regs lead consumption by 1 tile; loads for tile t+2
//       issued at tile t (compiler-counted vmcnt, never drained mid-loop).

#define LOADA(kbyte)                                                           \
  do {                                                                         \
    rA0 = *(const u16x8*)(ag0 + (kbyte));                                      \
    rA1 = *(const u16x8*)(ag1 + (kbyte));                                      \
    rA2 = *(const u16x8*)(ag0 + (kbyte) + 64);                                 \
    rA3 = *(const u16x8*)(ag1 + (kbyte) + 64);                                 \
  } while (0)

#define DSWA(parx)                                                             \
  do {                                                                         \
    unsigned short* S0_ = &lds[((parx) * 2 + 0) * SLOT];                       \
    unsigned short* S1_ = &lds[((parx) * 2 + 1) * SLOT];                       \
    *(u16x8*)(S0_ + sw0) = rA0;                                                \
    *(u16x8*)(S0_ + sw1) = rA1;                                                \
    *(u16x8*)(S1_ + sw0) = rA2;                                                \
    *(u16x8*)(S1_ + sw1) = rA3;                                                \
  } while (0)

#define LOADB(ktv)                                                             \
  do {                                                                         \
    _Pragma("unroll")                                                          \
    for (int u = 0; u < 4; u++)                                                \
      _Pragma("unroll")                                                        \
      for (int j = 0; j < 8; j++)                                              \
        rB[u][j] = bgu[u][(size_t)((ktv) + j) * BNN];                          \
  } while (0)

#define DSWB(parx)                                                             \
  do {                                                                         \
    unsigned short* SB_ = &lds[4 * SLOT + ((parx) * 2 + bh) * SLOT];           \
    _Pragma("unroll")                                                          \
    for (int u = 0; u < 4; u++) {                                              \
      u16x8 v_;                                                                \
      _Pragma("unroll")                                                        \
      for (int j = 0; j < 8; j++) v_[j] = f2bf(rB[u][j]);                      \
      *(u16x8*)(SB_ + brow * 32 + (u ^ bqx) * 8) = v_;                         \
    }                                                                          \
  } while (0)

#define COMPUTE(parx, hx)                                                      \
  do {                                                                         \
    const unsigned short* As_ = &lds[((parx) * 2 + (hx)) * SLOT];              \
    const unsigned short* Bs_ = &lds[4 * SLOT + ((parx) * 2 + (hx)) * SLOT];   \
    bf16x8 af[8], bfv[4];                                                      \
    _Pragma("unroll")                                                          \
    for (int mf = 0; mf < 8; mf++)                                             \
      af[mf] = *(const bf16x8*)(As_ + (wr * 128 + mf * 16 + lrow) * 32 + qsw); \
    _Pragma("unroll")                                                          \
    for (int nf = 0; nf < 4; nf++)                                             \
      bfv[nf] = *(const bf16x8*)(Bs_ + (wc * 64 + nf * 16 + lrow) * 32 + qsw); \
    __builtin_amdgcn_s_setprio(1);                                             \
    _Pragma("unroll")                                                          \
    for (int mf = 0; mf < 8; mf++)                                             \
      _Pragma("unroll")                                                        \
      for (int nf = 0; nf < 4; nf++)                                           \
        acc[mf][nf] = __builtin_amdgcn_mfma_f32_16x16x32_bf16(                 \
            af[mf], bfv[nf], acc[mf][nf], 0, 0, 0);                            \
    __builtin_amdgcn_s_setprio(0);                                             \
  } while (0)

#define SBAR asm volatile("s_barrier" ::: "memory")

#define GEMM_MAIN_LOOP(NT)                                                     \
  u16x8 rA0, rA1, rA2, rA3; float rB[4][8];                                    \
  LOADA(0); LOADB(0);                                                          \
  DSWA(0); DSWB(0);                                                            \
  LOADA(128); LOADB(64);                                                       \
  asm volatile("s_waitcnt lgkmcnt(0)" ::: "memory");                           \
  for (int tt = 0; tt < (NT); ++tt) {                                          \
    const int par = tt & 1;                                                    \
    SBAR;                                                                      \
    if (tt + 1 < (NT)) { DSWA(par ^ 1); DSWB(par ^ 1); }                       \
    if (tt + 2 < (NT)) { LOADA((tt + 2) * 128); LOADB((tt + 2) * 64); }        \
    COMPUTE(par, 0);                                                           \
    COMPUTE(par, 1);                                                           \
  }

// ---------------- GEMM1: H[pair] = relu(xb[token] @ w1[e] + b1[e]) ----------
__global__ __launch_bounds__(512, 2) void gemm1_8p_kernel(
    const unsigned short* __restrict__ xb, const float* __restrict__ w1f,
    const float* __restrict__ b1, const int* __restrict__ counts,
    const int* __restrict__ lists, unsigned short* __restrict__ Hb)
{
  int bx, by, bz;
  xcd_remap(bx, by, bz);
  const int e = bz;
  int cnt = counts[e]; if (cnt > CAP) cnt = CAP;
  const int m0 = by * BMG;
  if (m0 >= cnt) return;
  const int n0 = bx * BNG;
  const int* list = lists + e * CAP;
  const float* Wf = w1f + (size_t)e * CDIM * HDIM;
  const int BNN = HDIM;

  __shared__ __align__(16) unsigned short lds[8 * SLOT];  // 128 KB

  const int t = threadIdx.x, w = t >> 6, lane = t & 63;
  const int wr = w >> 2, wc = w & 3;          // 2M x 4N waves, each 128x64
  const int lrow = lane & 15, lgrp = lane >> 4;
  const int qsw = (lgrp ^ ((lrow >> 1) & 3)) * 8;

  // A staging (bf16, gathered rows)
  const int sr0 = w * 16 + (lane >> 2), sr1 = 128 + sr0;
  const int wq = ((lane & 3) ^ ((lane >> 3) & 3)) * 8;
  const int sw0 = sr0 * 32 + wq, sw1 = sr1 * 32 + wq;
  int ai0 = m0 + sr0; if (ai0 > cnt - 1) ai0 = cnt - 1;
  int ai1 = m0 + sr1; if (ai1 > cnt - 1) ai1 = cnt - 1;
  const char* ag0 = (const char*)(xb + (size_t)(list[ai0] >> 1) * CDIM) + (lane & 3) * 16;
  const char* ag1 = (const char*)(xb + (size_t)(list[ai1] >> 1) * CDIM) + (lane & 3) * 16;

  // B staging (fp32 [k][n] -> bf16 [n][k])
  const int brow = t & 255, bh = t >> 8, bqx = (brow >> 1) & 3;
  const float* bgu[4];
#pragma unroll
  for (int u = 0; u < 4; u++)
    bgu[u] = Wf + (size_t)(bh * 32 + u * 8) * BNN + n0 + brow;

  f32x4 acc[8][4] = {};

  GEMM_MAIN_LOOP(CDIM / 64)

  // epilogue: +b1, relu, bf16 scatter to Hb rows = pair ids
  int hrow[8][4]; bool valid[8][4];
#pragma unroll
  for (int mf = 0; mf < 8; mf++)
#pragma unroll
    for (int rr = 0; rr < 4; rr++) {
      const int mi = m0 + wr * 128 + mf * 16 + lgrp * 4 + rr;
      valid[mf][rr] = (mi < cnt);
      hrow[mf][rr] = list[valid[mf][rr] ? mi : (cnt - 1)];
    }
#pragma unroll
  for (int nf = 0; nf < 4; nf++) {
    const int col = n0 + wc * 64 + nf * 16 + lrow;
    const float bias = b1[e * HDIM + col];
#pragma unroll
    for (int mf = 0; mf < 8; mf++)
#pragma unroll
      for (int rr = 0; rr < 4; rr++)
        if (valid[mf][rr]) {
          float h = acc[mf][nf][rr] + bias;
          h = h > 0.f ? h : 0.f;
          Hb[(size_t)hrow[mf][rr] * HDIM + col] = f2bf(h);
        }
  }
}

// ---------------- GEMM2: out[token] += w_pair*(Hb[pair] @ w2[e] + b2) -------
__global__ __launch_bounds__(512, 2) void gemm2_8p_kernel(
    const unsigned short* __restrict__ Hb, const float* __restrict__ w2f,
    const float* __restrict__ b2, const float* __restrict__ pair_w,
    const int* __restrict__ counts, const int* __restrict__ lists,
    float* __restrict__ out)
{
  int bx, by, bz;
  xcd_remap(bx, by, bz);
  const int e = bz / KS2, ks = bz % KS2;
  int cnt = counts[e]; if (cnt > CAP) cnt = CAP;
  const int m0 = by * BMG;
  if (m0 >= cnt) return;
  const int n0 = bx * BNG;
  const int* list = lists + e * CAP;
  const float* Wf = w2f + (size_t)e * HDIM * CDIM;
  const int BNN = CDIM;
  const int kbeg = ks * (HDIM / KS2);

  __shared__ __align__(16) unsigned short lds[8 * SLOT];  // 128 KB

  const int t = threadIdx.x, w = t >> 6, lane = t & 63;
  const int wr = w >> 2, wc = w & 3;
  const int lrow = lane & 15, lgrp = lane >> 4;
  const int qsw = (lgrp ^ ((lrow >> 1) & 3)) * 8;

  const int sr0 = w * 16 + (lane >> 2), sr1 = 128 + sr0;
  const int wq = ((lane & 3) ^ ((lane >> 3) & 3)) * 8;
  const int sw0 = sr0 * 32 + wq, sw1 = sr1 * 32 + wq;
  int ai0 = m0 + sr0; if (ai0 > cnt - 1) ai0 = cnt - 1;
  int ai1 = m0 + sr1; if (ai1 > cnt - 1) ai1 = cnt - 1;
  const char* ag0 = (const char*)(Hb + (size_t)list[ai0] * HDIM + kbeg) + (lane & 3) * 16;
  const char* ag1 = (const char*)(Hb + (size_t)list[ai1] * HDIM + kbeg) + (lane & 3) * 16;

  const int brow = t & 255, bh = t >> 8, bqx = (brow >> 1) & 3;
  const float* bgu[4];
#pragma unroll
  for (int u = 0; u < 4; u++)
    bgu[u] = Wf + (size_t)(kbeg + bh * 32 + u * 8) * BNN + n0 + brow;

  f32x4 acc[8][4] = {};

  GEMM_MAIN_LOOP((HDIM / KS2) / 64)

  // epilogue: +b2 (ks==0 only), scale by routing weight, atomic accumulate.
  float wgt[8][4]; int tok[8][4]; bool valid[8][4];
#pragma unroll
  for (int mf = 0; mf < 8; mf++)
#pragma unroll
    for (int rr = 0; rr < 4; rr++) {
      const int mi = m0 + wr * 128 + mf * 16 + lgrp * 4 + rr;
      valid[mf][rr] = (mi < cnt);
      const int p = list[valid[mf][rr] ? mi : (cnt - 1)];
      wgt[mf][rr] = pair_w[p];
      tok[mf][rr] = p >> 1;
    }
#pragma unroll
  for (int nf = 0; nf < 4; nf++) {
    const int col = n0 + wc * 64 + nf * 16 + lrow;
    const float bias = (ks == 0) ? b2[e * CDIM + col] : 0.f;
#pragma unroll
    for (int mf = 0; mf < 8; mf++)
#pragma unroll
      for (int rr = 0; rr < 4; rr++)
        if (valid[mf][rr])
          atomicAdd(out + (size_t)tok[mf][rr] * CDIM + col,
                    wgt[mf][rr] * (acc[mf][nf][rr] + bias));
  }
}

// ================= fallback kernels (fp32 inputs, reg-staged, 128²) =========
__device__ __forceinline__ int swz(int row, int b) {
  return row * 128 + (b ^ (((row >> 1) & 7) << 4));
}

#define MFMA_COMPUTE_F(Abase, Bbase)                                           \
  _Pragma("unroll")                                                            \
  for (int kk = 0; kk < 2; kk++) {                                             \
    bf16x8 af[4], bfr[4];                                                      \
    const int kb = (kk * 32 + lgrp * 8) * 2;                                   \
    _Pragma("unroll")                                                          \
    for (int i = 0; i < 4; i++)                                                \
      af[i] = *(const bf16x8*)((Abase) + swz(wm + i * 16 + lrow, kb));         \
    _Pragma("unroll")                                                          \
    for (int j = 0; j < 4; j++)                                                \
      bfr[j] = *(const bf16x8*)((Bbase) + swz(wn + j * 16 + lrow, kb));        \
    _Pragma("unroll")                                                          \
    for (int i = 0; i < 4; i++)                                                \
      _Pragma("unroll")                                                        \
      for (int j = 0; j < 4; j++)                                              \
        acc[i][j] = __builtin_amdgcn_mfma_f32_16x16x32_bf16(                   \
            af[i], bfr[j], acc[i][j], 0, 0, 0);                                \
  }

__global__ __launch_bounds__(256) void gemm1_f32_kernel(
    const float* __restrict__ x, const float* __restrict__ w1,
    const float* __restrict__ b1, const int* __restrict__ counts,
    const int* __restrict__ lists, unsigned short* __restrict__ Hb,
    int e_base, int h_by_pair)
{
  const int e = e_base + blockIdx.z;
  int cnt = counts[e]; if (cnt > CAP) cnt = CAP;
  const int m0 = blockIdx.y * 128;
  if (m0 >= cnt) return;
  const int n0 = blockIdx.x * 128;
  const int* list = lists + e * CAP;
  const float* W = w1 + (size_t)e * CDIM * HDIM;
  __shared__ __align__(16) unsigned short As[128 * 64];
  __shared__ __align__(16) unsigned short Bs[128 * 64];
  const int t = threadIdx.x;
  const int a_row = t >> 1, a_half = t & 1;
  int a_idx = m0 + a_row; if (a_idx > cnt - 1) a_idx = cnt - 1;
  const float* a_src = x + (size_t)(list[a_idx] >> 1) * CDIM + a_half * 32;
  const int b_np = t & 63, b_kg = t >> 6;
  const int wid = t >> 6, lane = t & 63;
  const int wm = (wid >> 1) * 64, wn = (wid & 1) * 64;
  const int lrow = lane & 15, lgrp = lane >> 4;
  f32x4 acc[4][4] = {};
  for (int kt = 0; kt < CDIM; kt += 64) {
    {
      const float* s = a_src + kt;
      u16x8 cv[4];
#pragma unroll
      for (int q = 0; q < 4; q++) {
        float4 v0 = *(const float4*)(s + q * 8);
        float4 v1 = *(const float4*)(s + q * 8 + 4);
        cv[q][0] = f2bf(v0.x); cv[q][1] = f2bf(v0.y);
        cv[q][2] = f2bf(v0.z); cv[q][3] = f2bf(v0.w);
        cv[q][4] = f2bf(v1.x); cv[q][5] = f2bf(v1.y);
        cv[q][6] = f2bf(v1.z); cv[q][7] = f2bf(v1.w);
      }
#pragma unroll
      for (int q = 0; q < 4; q++)
        *(u16x8*)((char*)As + swz(a_row, (a_half * 32 + q * 8) * 2)) = cv[q];
    }
    {
#pragma unroll
      for (int it = 0; it < 2; it++) {
        const int k0 = (b_kg + 4 * it) * 8;
        u16x8 c0, c1;
#pragma unroll
        for (int j = 0; j < 8; j++) {
          float2 v = *(const float2*)(W + (size_t)(kt + k0 + j) * HDIM + n0 + 2 * b_np);
          c0[j] = f2bf(v.x); c1[j] = f2bf(v.y);
        }
        *(u16x8*)((char*)Bs + swz(2 * b_np,     k0 * 2)) = c0;
        *(u16x8*)((char*)Bs + swz(2 * b_np + 1, k0 * 2)) = c1;
      }
    }
    __syncthreads();
    MFMA_COMPUTE_F((const char*)As, (const char*)Bs)
    __syncthreads();
  }
  int hrow[4][4]; bool valid[4][4];
#pragma unroll
  for (int i = 0; i < 4; i++)
#pragma unroll
    for (int r = 0; r < 4; r++) {
      const int mi = m0 + wm + i * 16 + lgrp * 4 + r;
      valid[i][r] = (mi < cnt);
      const int idx = valid[i][r] ? mi : (cnt - 1);
      hrow[i][r] = h_by_pair ? list[idx] : idx;
    }
#pragma unroll
  for (int j = 0; j < 4; j++) {
    const int col = n0 + wn + j * 16 + lrow;
    const float bias = b1[e * HDIM + col];
#pragma unroll
    for (int i = 0; i < 4; i++)
#pragma unroll
      for (int r = 0; r < 4; r++)
        if (valid[i][r]) {
          float h = acc[i][j][r] + bias;
          h = h > 0.f ? h : 0.f;
          Hb[(size_t)hrow[i][r] * HDIM + col] = f2bf(h);
        }
  }
}

__global__ __launch_bounds__(256) void gemm2_f32_kernel(
    const unsigned short* __restrict__ Hb, const float* __restrict__ w2,
    const float* __restrict__ b2, const float* __restrict__ pair_w,
    const int* __restrict__ counts, const int* __restrict__ lists,
    float* __restrict__ out, int e_base, int h_by_pair)
{
  const int e = e_base + blockIdx.z;
  int cnt = counts[e]; if (cnt > CAP) cnt = CAP;
  const int m0 = blockIdx.y * 128;
  if (m0 >= cnt) return;
  const int n0 = blockIdx.x * 128;
  const int* list = lists + e * CAP;
  const float* W = w2 + (size_t)e * HDIM * CDIM;
  __shared__ __align__(16) unsigned short As[128 * 64];
  __shared__ __align__(16) unsigned short Bs[128 * 64];
  const int t = threadIdx.x;
  const int a_row = t >> 1, a_half = t & 1;
  int a_idx = m0 + a_row; if (a_idx > cnt - 1) a_idx = cnt - 1;
  const unsigned short* a_src =
      Hb + (size_t)(h_by_pair ? list[a_idx] : a_idx) * HDIM + a_half * 32;
  const int b_np = t & 63, b_kg = t >> 6;
  const int wid = t >> 6, lane = t & 63;
  const int wm = (wid >> 1) * 64, wn = (wid & 1) * 64;
  const int lrow = lane & 15, lgrp = lane >> 4;
  f32x4 acc[4][4] = {};
  for (int kt = 0; kt < HDIM; kt += 64) {
    {
      const unsigned short* s = a_src + kt;
#pragma unroll
      for (int q = 0; q < 4; q++) {
        u16x8 v = *(const u16x8*)(s + q * 8);
        *(u16x8*)((char*)As + swz(a_row, (a_half * 32 + q * 8) * 2)) = v;
      }
    }
    {
#pragma unroll
      for (int it = 0; it < 2; it++) {
        const int k0 = (b_kg + 4 * it) * 8;
        u16x8 c0, c1;
#pragma unroll
        for (int j = 0; j < 8; j++) {
          float2 v = *(const float2*)(W + (size_t)(kt + k0 + j) * CDIM + n0 + 2 * b_np);
          c0[j] = f2bf(v.x); c1[j] = f2bf(v.y);
        }
        *(u16x8*)((char*)Bs + swz(2 * b_np,     k0 * 2)) = c0;
        *(u16x8*)((char*)Bs + swz(2 * b_np + 1, k0 * 2)) = c1;
      }
    }
    __syncthreads();
    MFMA_COMPUTE_F((const char*)As, (const char*)Bs)
    __syncthreads();
  }
  float wgt[4][4]; int tok[4][4]; bool valid[4][4];
#pragma unroll
  for (int i = 0; i < 4; i++)
#pragma unroll
    for (int r = 0; r < 4; r++) {
      const int mi = m0 + wm + i * 16 + lgrp * 4 + r;
      valid[i][r] = (mi < cnt);
      const int idx = valid[i][r] ? mi : (cnt - 1);
      const int p = list[idx];
      wgt[i][r] = pair_w[p];
      tok[i][r] = p >> 1;
    }
#pragma unroll
  for (int j = 0; j < 4; j++) {
    const int col = n0 + wn + j * 16 + lrow;
    const float bias = b2[e * CDIM + col];
#pragma unroll
    for (int i = 0; i < 4; i++)
#pragma unroll
      for (int r = 0; r < 4; r++)
        if (valid[i][r])
          atomicAdd(out + (size_t)tok[i][r] * CDIM + col,
                    wgt[i][r] * (acc[i][j][r] + bias));
  }
}

extern "C" void kernel_launch(void* const* d_in, const int* in_sizes, int n_in,
                              void* d_out, int out_size, void* d_ws, size_t ws_size,
                              hipStream_t stream)
{
  const float* x  = (const float*)d_in[0];
  const float* wr = (const float*)d_in[1];
  const float* w1 = (const float*)d_in[2];
  const float* b1 = (const float*)d_in[3];
  const float* w2 = (const float*)d_in[4];
  const float* b2 = (const float*)d_in[5];
  float* out = (float*)d_out;

  const int N = in_sizes[0] / CDIM;  // 8192 tokens

  char* ws = (char*)d_ws;
  int* counts = (int*)ws;
  int* lists  = (int*)(ws + 256);
  float* pw   = (float*)(ws + 256 + NEXP * CAP * 4);
  size_t off = 256 + (size_t)NEXP * CAP * 4 + (size_t)2 * N * 4;
  off = (off + 255) & ~(size_t)255;
  unsigned short* xb = (unsigned short*)(ws + off);
  const size_t xb_sz = (size_t)N * CDIM * 2;
  unsigned short* Hb = (unsigned short*)(ws + off + xb_sz);
  const size_t Hb_sz = (size_t)2 * N * HDIM * 2;

  const size_t need_new = off + xb_sz + Hb_sz;             // ~151 MB
  const size_t need_old = off + Hb_sz;                     // ~134.5 MB

  hipMemsetAsync(d_ws, 0, 64, stream);
  hipMemsetAsync(d_out, 0, (size_t)out_size * 4, stream);

  if (ws_size >= need_new) {
    router_kernel<<<N / 4, 256, 0, stream>>>(x, wr, pw, counts, lists, xb);
    gemm1_8p_kernel<<<dim3(HDIM / BNG, CAP / BMG, NEXP), 512, 0, stream>>>(
        xb, w1, b1, counts, lists, Hb);
    gemm2_8p_kernel<<<dim3(CDIM / BNG, CAP / BMG, NEXP * KS2), 512, 0, stream>>>(
        Hb, w2, b2, pw, counts, lists, out);
  } else if (ws_size >= need_old) {
    unsigned short* Hb0 = (unsigned short*)(ws + off);
    router_kernel<<<N / 4, 256, 0, stream>>>(x, wr, pw, counts, lists, Hb0);
    gemm1_f32_kernel<<<dim3(HDIM / 128, CAP / 128, NEXP), 256, 0, stream>>>(
        x, w1, b1, counts, lists, Hb0, 0, 1);
    gemm2_f32_kernel<<<dim3(CDIM / 128, CAP / 128, NEXP), 256, 0, stream>>>(
        Hb0, w2, b2, pw, counts, lists, out, 0, 1);
  }
}